// Round 1
// baseline (2626.121 us; speedup 1.0000x reference)
//
#include <hip/hip_runtime.h>

#define N_NODES 500000
#define N_EDGES 8000000
#define N_GRAPHS 4096

// ---------------- degree / norm precompute ----------------

__global__ void k_deg_init(float* __restrict__ deg) {
    int i = blockIdx.x * blockDim.x + threadIdx.x;
    if (i < N_NODES) deg[i] = 1.0f;  // self-loop weight
}

__global__ void k_deg_accum(const int* __restrict__ col, const float* __restrict__ w,
                            float* __restrict__ deg) {
    int e = blockIdx.x * blockDim.x + threadIdx.x;
    int stride = gridDim.x * blockDim.x;
    for (; e < N_EDGES; e += stride)
        atomicAdd(&deg[col[e]], w[e]);
}

__global__ void k_dinv(float* __restrict__ deg) {
    int i = blockIdx.x * blockDim.x + threadIdx.x;
    if (i < N_NODES) deg[i] = rsqrtf(deg[i]);  // deg >= 1 always
}

__global__ void k_norm(const int* __restrict__ row, const int* __restrict__ col,
                       const float* __restrict__ w, const float* __restrict__ dinv,
                       float* __restrict__ nrm) {
    int e = blockIdx.x * blockDim.x + threadIdx.x;
    int stride = gridDim.x * blockDim.x;
    for (; e < N_EDGES; e += stride)
        nrm[e] = dinv[row[e]] * w[e] * dinv[col[e]];
}

// ---------------- feature transforms ----------------

// layer 1 matmul: x[N,9] @ W1[9,8] -> out[N,8]  (no bias/relu on input)
__global__ void k_mm1(const float* __restrict__ x, const float* __restrict__ W,
                      float* __restrict__ out) {
    int i = blockIdx.x * blockDim.x + threadIdx.x;
    if (i >= N_NODES) return;
    float xi[9];
#pragma unroll
    for (int f = 0; f < 9; f++) xi[f] = x[i * 9 + f];
    float o[8];
#pragma unroll
    for (int fo = 0; fo < 8; fo++) o[fo] = 0.0f;
#pragma unroll
    for (int fi = 0; fi < 9; fi++) {
        float a = xi[fi];
#pragma unroll
        for (int fo = 0; fo < 8; fo++) o[fo] += a * W[fi * 8 + fo];
    }
    float4* po = reinterpret_cast<float4*>(out + i * 8);
    po[0] = make_float4(o[0], o[1], o[2], o[3]);
    po[1] = make_float4(o[4], o[5], o[6], o[7]);
}

// fused: h = relu(acc + b); out = h @ W   (FIN, FOUT multiples of 4)
template <int FIN, int FOUT>
__global__ void k_mm_relu(const float* __restrict__ hin, const float* __restrict__ b,
                          const float* __restrict__ W, float* __restrict__ hout) {
    int i = blockIdx.x * blockDim.x + threadIdx.x;
    if (i >= N_NODES) return;
    float a[FIN];
    const float4* p = reinterpret_cast<const float4*>(hin + i * FIN);
#pragma unroll
    for (int q = 0; q < FIN / 4; q++) {
        float4 v = p[q];
        a[q * 4 + 0] = v.x; a[q * 4 + 1] = v.y; a[q * 4 + 2] = v.z; a[q * 4 + 3] = v.w;
    }
#pragma unroll
    for (int fi = 0; fi < FIN; fi++) a[fi] = fmaxf(a[fi] + b[fi], 0.0f);
    float o[FOUT];
#pragma unroll
    for (int fo = 0; fo < FOUT; fo++) o[fo] = 0.0f;
#pragma unroll
    for (int fi = 0; fi < FIN; fi++) {
        float av = a[fi];
#pragma unroll
        for (int fo = 0; fo < FOUT; fo++) o[fo] += av * W[fi * FOUT + fo];
    }
    float4* po = reinterpret_cast<float4*>(hout + i * FOUT);
#pragma unroll
    for (int q = 0; q < FOUT / 4; q++)
        po[q] = make_float4(o[q * 4 + 0], o[q * 4 + 1], o[q * 4 + 2], o[q * 4 + 3]);
}

// ---------------- self-loop init (fuses zero-init + self-loop message) ----------------

template <int LOGF>
__global__ void k_selfloop(const float* __restrict__ dinv, const float* __restrict__ xw,
                           float* __restrict__ outb) {
    int t = blockIdx.x * blockDim.x + threadIdx.x;
    if (t >= (N_NODES << LOGF)) return;
    float d = dinv[t >> LOGF];
    outb[t] = d * d * xw[t];
}

// ---------------- edge scatter: out[col] += norm * xw[row] ----------------
// lane-per-feature: F consecutive threads share an edge -> edge loads broadcast,
// gather + atomic each touch one contiguous segment.

template <int LOGF>
__global__ void k_scatter(const int* __restrict__ row, const int* __restrict__ col,
                          const float* __restrict__ nrm, const float* __restrict__ xw,
                          float* __restrict__ outb) {
    const int F = 1 << LOGF;
    const int total = N_EDGES << LOGF;
    int t = blockIdx.x * blockDim.x + threadIdx.x;
    int stride = gridDim.x * blockDim.x;
    for (; t < total; t += stride) {
        int e = t >> LOGF;
        int f = t & (F - 1);
        float nv = nrm[e];
        int r = row[e];
        int c = col[e];
        atomicAdd(&outb[(c << LOGF) + f], nv * xw[(r << LOGF) + f]);
    }
}

// ---------------- pooling ----------------

__global__ void k_pool(const float* __restrict__ h, const int* __restrict__ batch,
                       float* __restrict__ psum, float* __restrict__ pcnt) {
    int t = blockIdx.x * blockDim.x + threadIdx.x;
    if (t >= (N_NODES << 5)) return;
    int i = t >> 5;
    int f = t & 31;
    int g = batch[i];
    atomicAdd(&psum[(g << 5) + f], h[t]);
    if (f == 0) atomicAdd(&pcnt[g], 1.0f);
}

// final: out[g] = (cnt>0 ? psum/cnt + b3 : 0) @ Wl + bl
__global__ void k_final(const float* __restrict__ psum, const float* __restrict__ pcnt,
                        const float* __restrict__ b3, const float* __restrict__ Wl,
                        const float* __restrict__ bl, float* __restrict__ out) {
    int g = blockIdx.x * blockDim.x + threadIdx.x;
    if (g >= N_GRAPHS) return;
    float cnt = pcnt[g];
    float o0 = bl[0], o1 = bl[1];
    if (cnt > 0.0f) {
        float inv = 1.0f / cnt;
#pragma unroll
        for (int fo = 0; fo < 32; fo++) {
            float p = psum[(g << 5) + fo] * inv + b3[fo];
            o0 += p * Wl[fo * 2 + 0];
            o1 += p * Wl[fo * 2 + 1];
        }
    }
    out[g * 2 + 0] = o0;
    out[g * 2 + 1] = o1;
}

// ---------------- launch ----------------

static inline int nblk(long n, int b) { return (int)((n + b - 1) / b); }

extern "C" void kernel_launch(void* const* d_in, const int* in_sizes, int n_in,
                              void* d_out, int out_size, void* d_ws, size_t ws_size,
                              hipStream_t stream) {
    const float* x     = (const float*)d_in[0];
    const int*   ei    = (const int*)d_in[1];
    const float* ew    = (const float*)d_in[2];
    const int*   batch = (const int*)d_in[3];
    const float* W1 = (const float*)d_in[4];
    const float* b1 = (const float*)d_in[5];
    const float* W2 = (const float*)d_in[6];
    const float* b2 = (const float*)d_in[7];
    const float* W3 = (const float*)d_in[8];
    const float* b3 = (const float*)d_in[9];
    const float* Wl = (const float*)d_in[10];
    const float* bl = (const float*)d_in[11];
    float* out = (float*)d_out;

    const int* row = ei;            // edge_index[0]
    const int* col = ei + N_EDGES;  // edge_index[1]

    // workspace layout (floats)
    float* deg  = (float*)d_ws;            // 500000 (becomes dinv in place)
    float* nrm  = deg + 512000;            // 8M
    float* bufA = nrm + 8000000;           // 16M (xw buffer)
    float* bufB = bufA + 16000000;         // 16M (accumulator / h buffer)
    float* psum = bufB + 16000000;         // 4096*32
    float* pcnt = psum + (N_GRAPHS * 32);  // 4096

    const int B = 256;

    // norm precompute
    k_deg_init<<<nblk(N_NODES, B), B, 0, stream>>>(deg);
    k_deg_accum<<<2048, B, 0, stream>>>(col, ew, deg);
    k_dinv<<<nblk(N_NODES, B), B, 0, stream>>>(deg);
    k_norm<<<2048, B, 0, stream>>>(row, col, ew, deg, nrm);

    // zero pooling buffers early (contiguous psum+pcnt)
    hipMemsetAsync(psum, 0, (N_GRAPHS * 32 + N_GRAPHS) * sizeof(float), stream);

    // layer 1: F 9->8
    k_mm1<<<nblk(N_NODES, B), B, 0, stream>>>(x, W1, bufA);
    k_selfloop<3><<<nblk((long)N_NODES * 8, B), B, 0, stream>>>(deg, bufA, bufB);
    k_scatter<3><<<4096, B, 0, stream>>>(row, col, nrm, bufA, bufB);

    // layer 2: F 8->16 (bias+relu fused into matmul)
    k_mm_relu<8, 16><<<nblk(N_NODES, B), B, 0, stream>>>(bufB, b1, W2, bufA);
    k_selfloop<4><<<nblk((long)N_NODES * 16, B), B, 0, stream>>>(deg, bufA, bufB);
    k_scatter<4><<<4096, B, 0, stream>>>(row, col, nrm, bufA, bufB);

    // layer 3: F 16->32
    k_mm_relu<16, 32><<<nblk(N_NODES, B), B, 0, stream>>>(bufB, b2, W3, bufA);
    k_selfloop<5><<<nblk((long)N_NODES * 32, B), B, 0, stream>>>(deg, bufA, bufB);
    k_scatter<5><<<8192, B, 0, stream>>>(row, col, nrm, bufA, bufB);

    // pool (b3 folded into k_final) + classifier
    k_pool<<<nblk((long)N_NODES * 32, B), B, 0, stream>>>(bufB, batch, psum, pcnt);
    k_final<<<nblk(N_GRAPHS, B), B, 0, stream>>>(psum, pcnt, b3, Wl, bl, out);
}

// Round 4
// 1964.468 us; speedup vs baseline: 1.3368x; 1.3368x over previous
//
#include <hip/hip_runtime.h>

#define N_NODES 500000
#define N_EDGES 8000000
#define N_GRAPHS 4096

// ---------------- init: deg=1 (self loop), cnt=0 ----------------

__global__ void k_init(float* __restrict__ deg, int* __restrict__ cnt) {
    int i = blockIdx.x * blockDim.x + threadIdx.x;
    if (i < N_NODES) { deg[i] = 1.0f; cnt[i] = 0; }
}

// histogram in-degree (count + weighted)
__global__ void k_hist(const int* __restrict__ col, const float* __restrict__ w,
                       int* __restrict__ cnt, float* __restrict__ deg) {
    int e = blockIdx.x * blockDim.x + threadIdx.x;
    int stride = gridDim.x * blockDim.x;
    for (; e < N_EDGES; e += stride) {
        int c = col[e];
        atomicAdd(&cnt[c], 1);
        atomicAdd(&deg[c], w[e]);
    }
}

__global__ void k_dinv(float* __restrict__ deg) {
    int i = blockIdx.x * blockDim.x + threadIdx.x;
    if (i < N_NODES) deg[i] = rsqrtf(deg[i]);  // deg >= 1 always
}

// ---------------- exclusive scan of cnt -> rowptr ----------------

#define SCAN_T 256
#define SCAN_E 4
#define SCAN_ELEMS (SCAN_T * SCAN_E)  // 1024
#define SCAN_NB ((N_NODES + SCAN_ELEMS - 1) / SCAN_ELEMS)  // 489

__global__ void k_scan1(const int* __restrict__ cnt, int* __restrict__ pre,
                        int* __restrict__ bsum) {
    __shared__ int sh[SCAN_T];
    int tid = threadIdx.x;
    int base = blockIdx.x * SCAN_ELEMS + tid * SCAN_E;
    int v[SCAN_E];
    int s = 0;
#pragma unroll
    for (int j = 0; j < SCAN_E; j++) {
        v[j] = (base + j < N_NODES) ? cnt[base + j] : 0;
        s += v[j];
    }
    sh[tid] = s;
    __syncthreads();
    for (int off = 1; off < SCAN_T; off <<= 1) {
        int t = (tid >= off) ? sh[tid - off] : 0;
        __syncthreads();
        sh[tid] += t;
        __syncthreads();
    }
    int run = (tid == 0) ? 0 : sh[tid - 1];
    if (tid == SCAN_T - 1) bsum[blockIdx.x] = sh[SCAN_T - 1];
#pragma unroll
    for (int j = 0; j < SCAN_E; j++) {
        if (base + j < N_NODES) pre[base + j] = run;
        run += v[j];
    }
}

#define SCAN2_T 512
__global__ void k_scan2(int* __restrict__ bsum) {
    __shared__ int sh[SCAN2_T];
    int tid = threadIdx.x;
    sh[tid] = (tid < SCAN_NB) ? bsum[tid] : 0;
    __syncthreads();
    for (int off = 1; off < SCAN2_T; off <<= 1) {
        int t = (tid >= off) ? sh[tid - off] : 0;
        __syncthreads();
        sh[tid] += t;
        __syncthreads();
    }
    int ex = (tid == 0) ? 0 : sh[tid - 1];
    if (tid < SCAN_NB) bsum[tid] = ex;
}

__global__ void k_scan3(int* __restrict__ pre, const int* __restrict__ bsum) {
    int i = blockIdx.x * blockDim.x + threadIdx.x;
    if (i < N_NODES) pre[i] += bsum[i / SCAN_ELEMS];
    if (i == 0) pre[N_NODES] = N_EDGES;
}

// ---------------- build CSR edge records: ebuf[pos] = {norm, row} ----------------

__global__ void k_build(const int* __restrict__ row, const int* __restrict__ col,
                        const float* __restrict__ w, const float* __restrict__ dinv,
                        const int* __restrict__ rowptr, int* __restrict__ cur,
                        float2* __restrict__ ebuf) {
    int e = blockIdx.x * blockDim.x + threadIdx.x;
    int stride = gridDim.x * blockDim.x;
    for (; e < N_EDGES; e += stride) {
        int c = col[e];
        int r = row[e];
        float nv = dinv[r] * w[e] * dinv[c];
        int idx = atomicSub(&cur[c], 1) - 1;  // any order within segment
        ebuf[rowptr[c] + idx] = make_float2(nv, __int_as_float(r));
    }
}

// ---------------- graph boundaries (batch is sorted) ----------------

__global__ void k_gstart(const int* __restrict__ batch, int* __restrict__ gstart) {
    int g = blockIdx.x * blockDim.x + threadIdx.x;
    if (g > N_GRAPHS) return;
    if (g == N_GRAPHS) { gstart[g] = N_NODES; return; }
    int lo = 0, hi = N_NODES;  // lower_bound: first i with batch[i] >= g
    while (lo < hi) {
        int mid = (lo + hi) >> 1;
        if (batch[mid] < g) lo = mid + 1; else hi = mid;
    }
    gstart[g] = lo;
}

// ---------------- feature transforms ----------------

__global__ void k_mm1(const float* __restrict__ x, const float* __restrict__ W,
                      float* __restrict__ out) {
    int i = blockIdx.x * blockDim.x + threadIdx.x;
    if (i >= N_NODES) return;
    float xi[9];
#pragma unroll
    for (int f = 0; f < 9; f++) xi[f] = x[i * 9 + f];
    float o[8];
#pragma unroll
    for (int fo = 0; fo < 8; fo++) o[fo] = 0.0f;
#pragma unroll
    for (int fi = 0; fi < 9; fi++) {
        float a = xi[fi];
#pragma unroll
        for (int fo = 0; fo < 8; fo++) o[fo] += a * W[fi * 8 + fo];
    }
    float4* po = reinterpret_cast<float4*>(out + i * 8);
    po[0] = make_float4(o[0], o[1], o[2], o[3]);
    po[1] = make_float4(o[4], o[5], o[6], o[7]);
}

template <int FIN, int FOUT>
__global__ void k_mm_relu(const float* __restrict__ hin, const float* __restrict__ b,
                          const float* __restrict__ W, float* __restrict__ hout) {
    int i = blockIdx.x * blockDim.x + threadIdx.x;
    if (i >= N_NODES) return;
    float a[FIN];
    const float4* p = reinterpret_cast<const float4*>(hin + i * FIN);
#pragma unroll
    for (int q = 0; q < FIN / 4; q++) {
        float4 v = p[q];
        a[q * 4 + 0] = v.x; a[q * 4 + 1] = v.y; a[q * 4 + 2] = v.z; a[q * 4 + 3] = v.w;
    }
#pragma unroll
    for (int fi = 0; fi < FIN; fi++) a[fi] = fmaxf(a[fi] + b[fi], 0.0f);
    float o[FOUT];
#pragma unroll
    for (int fo = 0; fo < FOUT; fo++) o[fo] = 0.0f;
#pragma unroll
    for (int fi = 0; fi < FIN; fi++) {
        float av = a[fi];
#pragma unroll
        for (int fo = 0; fo < FOUT; fo++) o[fo] += av * W[fi * FOUT + fo];
    }
    float4* po = reinterpret_cast<float4*>(hout + i * FOUT);
#pragma unroll
    for (int q = 0; q < FOUT / 4; q++)
        po[q] = make_float4(o[q * 4 + 0], o[q * 4 + 1], o[q * 4 + 2], o[q * 4 + 3]);
}

// ---------------- gather-reduce per layer (no atomics) ----------------
// F lanes share one output node: broadcast 8B edge record, coalesced 4F-byte
// row gather, coalesced output write. Self-loop term = accumulator init.

template <int LOGF>
__global__ void k_gather(const int* __restrict__ rowptr, const float2* __restrict__ ebuf,
                         const float* __restrict__ dinv, const float* __restrict__ xw,
                         float* __restrict__ out) {
    const int F = 1 << LOGF;
    int t = blockIdx.x * blockDim.x + threadIdx.x;
    int c = t >> LOGF;
    if (c >= N_NODES) return;
    int f = t & (F - 1);
    float d = dinv[c];
    float acc = d * d * xw[(c << LOGF) + f];
    int e0 = rowptr[c], e1 = rowptr[c + 1];
#pragma unroll 2
    for (int e = e0; e < e1; e++) {
        float2 rn = ebuf[e];
        int r = __float_as_int(rn.y);
        acc += rn.x * xw[(r << LOGF) + f];
    }
    out[t] = acc;
}

// ---------------- pooling (segment sums over sorted batch) ----------------

__global__ void k_pool2(const float* __restrict__ h, const int* __restrict__ gstart,
                        float* __restrict__ psum) {
    int t = blockIdx.x * blockDim.x + threadIdx.x;
    if (t >= (N_GRAPHS << 5)) return;
    int g = t >> 5;
    int f = t & 31;
    int s = gstart[g], e = gstart[g + 1];
    float acc = 0.0f;
    for (int i = s; i < e; i++) acc += h[(i << 5) + f];
    psum[t] = acc;
}

__global__ void k_final(const float* __restrict__ psum, const int* __restrict__ gstart,
                        const float* __restrict__ b3, const float* __restrict__ Wl,
                        const float* __restrict__ bl, float* __restrict__ out) {
    int g = blockIdx.x * blockDim.x + threadIdx.x;
    if (g >= N_GRAPHS) return;
    int cnt = gstart[g + 1] - gstart[g];
    float o0 = bl[0], o1 = bl[1];
    if (cnt > 0) {
        float inv = 1.0f / (float)cnt;
#pragma unroll
        for (int fo = 0; fo < 32; fo++) {
            float p = psum[(g << 5) + fo] * inv + b3[fo];
            o0 += p * Wl[fo * 2 + 0];
            o1 += p * Wl[fo * 2 + 1];
        }
    }
    out[g * 2 + 0] = o0;
    out[g * 2 + 1] = o1;
}

// ---------------- launch ----------------

static inline int nblk(long n, int b) { return (int)((n + b - 1) / b); }

extern "C" void kernel_launch(void* const* d_in, const int* in_sizes, int n_in,
                              void* d_out, int out_size, void* d_ws, size_t ws_size,
                              hipStream_t stream) {
    const float* x     = (const float*)d_in[0];
    const int*   ei    = (const int*)d_in[1];
    const float* ew    = (const float*)d_in[2];
    const int*   batch = (const int*)d_in[3];
    const float* W1 = (const float*)d_in[4];
    const float* b1 = (const float*)d_in[5];
    const float* W2 = (const float*)d_in[6];
    const float* b2 = (const float*)d_in[7];
    const float* W3 = (const float*)d_in[8];
    const float* b3 = (const float*)d_in[9];
    const float* Wl = (const float*)d_in[10];
    const float* bl = (const float*)d_in[11];
    float* out = (float*)d_out;

    const int* row = ei;            // edge_index[0]
    const int* col = ei + N_EDGES;  // edge_index[1]

    // workspace layout (float-sized slots, all 16B-aligned pads)
    float*  deg    = (float*)d_ws;               // 500224 (dinv in place)
    int*    cnt    = (int*)(deg + 500224);       // 500224 (cursor in k_build)
    int*    rowptr = (int*)(deg + 1000448);      // 500224 (uses 500001)
    float2* ebuf   = (float2*)(deg + 1500672);   // 8M float2 = 16M floats
    float*  bufA   = deg + 17500672;             // 16M
    float*  bufB   = deg + 33500672;             // 16M
    int*    bsum   = (int*)(deg + 49500672);     // 512
    int*    gstart = (int*)(deg + 49501184);     // 4104
    float*  psum   = deg + 49505288;             // 131072  (end ~198.5 MB)

    const int B = 256;

    // CSR build + norm precompute
    k_init<<<nblk(N_NODES, B), B, 0, stream>>>(deg, cnt);
    k_hist<<<2048, B, 0, stream>>>(col, ew, cnt, deg);
    k_dinv<<<nblk(N_NODES, B), B, 0, stream>>>(deg);
    k_scan1<<<SCAN_NB, SCAN_T, 0, stream>>>(cnt, rowptr, bsum);
    k_scan2<<<1, SCAN2_T, 0, stream>>>(bsum);
    k_scan3<<<nblk(N_NODES, B), B, 0, stream>>>(rowptr, bsum);
    k_build<<<2048, B, 0, stream>>>(row, col, ew, deg, rowptr, cnt, ebuf);
    k_gstart<<<nblk(N_GRAPHS + 1, B), B, 0, stream>>>(batch, gstart);

    // layer 1: 9 -> 8
    k_mm1<<<nblk(N_NODES, B), B, 0, stream>>>(x, W1, bufA);
    k_gather<3><<<nblk((long)N_NODES * 8, B), B, 0, stream>>>(rowptr, ebuf, deg, bufA, bufB);

    // layer 2: 8 -> 16
    k_mm_relu<8, 16><<<nblk(N_NODES, B), B, 0, stream>>>(bufB, b1, W2, bufA);
    k_gather<4><<<nblk((long)N_NODES * 16, B), B, 0, stream>>>(rowptr, ebuf, deg, bufA, bufB);

    // layer 3: 16 -> 32
    k_mm_relu<16, 32><<<nblk(N_NODES, B), B, 0, stream>>>(bufB, b2, W3, bufA);
    k_gather<5><<<nblk((long)N_NODES * 32, B), B, 0, stream>>>(rowptr, ebuf, deg, bufA, bufB);

    // pool + classifier
    k_pool2<<<nblk((long)N_GRAPHS * 32, B), B, 0, stream>>>(bufB, gstart, psum);
    k_final<<<nblk(N_GRAPHS, B), B, 0, stream>>>(psum, gstart, b3, Wl, bl, out);
}

// Round 5
// 1464.402 us; speedup vs baseline: 1.7933x; 1.3415x over previous
//
#include <hip/hip_runtime.h>

#define N_NODES 500000
#define N_EDGES 8000000
#define N_GRAPHS 4096

#define WSCALE 4294967296.0  // 2^32 fixed-point scale for weights
#define MASK44 ((1ULL << 44) - 1)

// ---------------- init: packed[i] = count 0 | weight 1.0 (self loop) ----------------

__global__ void k_init(unsigned long long* __restrict__ packed) {
    int i = blockIdx.x * blockDim.x + threadIdx.x;
    if (i < N_NODES) packed[i] = 1ULL << 32;  // deg = 1.0 fixed-point, count = 0
}

// ---------------- single atomic per edge: count++ (hi 20b) + deg += w (lo 44b) ----
// returned old>>44 is this edge's within-segment slot -> idx[e]

__global__ void k_hist(const int* __restrict__ col, const float* __restrict__ w,
                       unsigned long long* __restrict__ packed, int* __restrict__ idx) {
    int e = blockIdx.x * blockDim.x + threadIdx.x;
    int stride = gridDim.x * blockDim.x;
    for (; e < N_EDGES; e += stride) {
        unsigned long long wf = (unsigned long long)((double)w[e] * WSCALE + 0.5);
        unsigned long long add = (1ULL << 44) | wf;
        unsigned long long old = atomicAdd(&packed[col[e]], add);
        idx[e] = (int)(old >> 44);
    }
}

__global__ void k_dinv(const unsigned long long* __restrict__ packed,
                       float* __restrict__ dinv) {
    int i = blockIdx.x * blockDim.x + threadIdx.x;
    if (i < N_NODES) {
        float deg = (float)((double)(packed[i] & MASK44) * (1.0 / WSCALE));
        dinv[i] = rsqrtf(deg);  // deg >= 1 always
    }
}

// ---------------- exclusive scan of counts (packed >> 44) -> rowptr ----------------

#define SCAN_T 256
#define SCAN_E 4
#define SCAN_ELEMS (SCAN_T * SCAN_E)  // 1024
#define SCAN_NB ((N_NODES + SCAN_ELEMS - 1) / SCAN_ELEMS)  // 489

__global__ void k_scan1(const unsigned long long* __restrict__ packed,
                        int* __restrict__ pre, int* __restrict__ bsum) {
    __shared__ int sh[SCAN_T];
    int tid = threadIdx.x;
    int base = blockIdx.x * SCAN_ELEMS + tid * SCAN_E;
    int v[SCAN_E];
    int s = 0;
#pragma unroll
    for (int j = 0; j < SCAN_E; j++) {
        v[j] = (base + j < N_NODES) ? (int)(packed[base + j] >> 44) : 0;
        s += v[j];
    }
    sh[tid] = s;
    __syncthreads();
    for (int off = 1; off < SCAN_T; off <<= 1) {
        int t = (tid >= off) ? sh[tid - off] : 0;
        __syncthreads();
        sh[tid] += t;
        __syncthreads();
    }
    int run = (tid == 0) ? 0 : sh[tid - 1];
    if (tid == SCAN_T - 1) bsum[blockIdx.x] = sh[SCAN_T - 1];
#pragma unroll
    for (int j = 0; j < SCAN_E; j++) {
        if (base + j < N_NODES) pre[base + j] = run;
        run += v[j];
    }
}

#define SCAN2_T 512
__global__ void k_scan2(int* __restrict__ bsum) {
    __shared__ int sh[SCAN2_T];
    int tid = threadIdx.x;
    sh[tid] = (tid < SCAN_NB) ? bsum[tid] : 0;
    __syncthreads();
    for (int off = 1; off < SCAN2_T; off <<= 1) {
        int t = (tid >= off) ? sh[tid - off] : 0;
        __syncthreads();
        sh[tid] += t;
        __syncthreads();
    }
    int ex = (tid == 0) ? 0 : sh[tid - 1];
    if (tid < SCAN_NB) bsum[tid] = ex;
}

__global__ void k_scan3(int* __restrict__ pre, const int* __restrict__ bsum) {
    int i = blockIdx.x * blockDim.x + threadIdx.x;
    if (i < N_NODES) pre[i] += bsum[i / SCAN_ELEMS];
    if (i == 0) pre[N_NODES] = N_EDGES;
}

// ---------------- build CSR edge records (NO atomics): ebuf[pos] = {norm, row} -----

__global__ void k_build(const int* __restrict__ row, const int* __restrict__ col,
                        const float* __restrict__ w, const int* __restrict__ idx,
                        const float* __restrict__ dinv, const int* __restrict__ rowptr,
                        float2* __restrict__ ebuf) {
    int e = blockIdx.x * blockDim.x + threadIdx.x;
    int stride = gridDim.x * blockDim.x;
    for (; e < N_EDGES; e += stride) {
        int c = col[e];
        int r = row[e];
        float nv = dinv[r] * w[e] * dinv[c];
        ebuf[rowptr[c] + idx[e]] = make_float2(nv, __int_as_float(r));
    }
}

// ---------------- graph boundaries (batch is sorted) ----------------

__global__ void k_gstart(const int* __restrict__ batch, int* __restrict__ gstart) {
    int g = blockIdx.x * blockDim.x + threadIdx.x;
    if (g > N_GRAPHS) return;
    if (g == N_GRAPHS) { gstart[g] = N_NODES; return; }
    int lo = 0, hi = N_NODES;  // lower_bound: first i with batch[i] >= g
    while (lo < hi) {
        int mid = (lo + hi) >> 1;
        if (batch[mid] < g) lo = mid + 1; else hi = mid;
    }
    gstart[g] = lo;
}

// ---------------- feature transforms ----------------

__global__ void k_mm1(const float* __restrict__ x, const float* __restrict__ W,
                      float* __restrict__ out) {
    int i = blockIdx.x * blockDim.x + threadIdx.x;
    if (i >= N_NODES) return;
    float xi[9];
#pragma unroll
    for (int f = 0; f < 9; f++) xi[f] = x[i * 9 + f];
    float o[8];
#pragma unroll
    for (int fo = 0; fo < 8; fo++) o[fo] = 0.0f;
#pragma unroll
    for (int fi = 0; fi < 9; fi++) {
        float a = xi[fi];
#pragma unroll
        for (int fo = 0; fo < 8; fo++) o[fo] += a * W[fi * 8 + fo];
    }
    float4* po = reinterpret_cast<float4*>(out + i * 8);
    po[0] = make_float4(o[0], o[1], o[2], o[3]);
    po[1] = make_float4(o[4], o[5], o[6], o[7]);
}

template <int FIN, int FOUT>
__global__ void k_mm_relu(const float* __restrict__ hin, const float* __restrict__ b,
                          const float* __restrict__ W, float* __restrict__ hout) {
    int i = blockIdx.x * blockDim.x + threadIdx.x;
    if (i >= N_NODES) return;
    float a[FIN];
    const float4* p = reinterpret_cast<const float4*>(hin + i * FIN);
#pragma unroll
    for (int q = 0; q < FIN / 4; q++) {
        float4 v = p[q];
        a[q * 4 + 0] = v.x; a[q * 4 + 1] = v.y; a[q * 4 + 2] = v.z; a[q * 4 + 3] = v.w;
    }
#pragma unroll
    for (int fi = 0; fi < FIN; fi++) a[fi] = fmaxf(a[fi] + b[fi], 0.0f);
    float o[FOUT];
#pragma unroll
    for (int fo = 0; fo < FOUT; fo++) o[fo] = 0.0f;
#pragma unroll
    for (int fi = 0; fi < FIN; fi++) {
        float av = a[fi];
#pragma unroll
        for (int fo = 0; fo < FOUT; fo++) o[fo] += av * W[fi * FOUT + fo];
    }
    float4* po = reinterpret_cast<float4*>(hout + i * FOUT);
#pragma unroll
    for (int q = 0; q < FOUT / 4; q++)
        po[q] = make_float4(o[q * 4 + 0], o[q * 4 + 1], o[q * 4 + 2], o[q * 4 + 3]);
}

// ---------------- gather-reduce per layer (no atomics) ----------------

template <int LOGF>
__global__ void k_gather(const int* __restrict__ rowptr, const float2* __restrict__ ebuf,
                         const float* __restrict__ dinv, const float* __restrict__ xw,
                         float* __restrict__ out) {
    const int F = 1 << LOGF;
    int t = blockIdx.x * blockDim.x + threadIdx.x;
    int c = t >> LOGF;
    if (c >= N_NODES) return;
    int f = t & (F - 1);
    float d = dinv[c];
    float acc = d * d * xw[(c << LOGF) + f];
    int e0 = rowptr[c], e1 = rowptr[c + 1];
#pragma unroll 2
    for (int e = e0; e < e1; e++) {
        float2 rn = ebuf[e];
        int r = __float_as_int(rn.y);
        acc += rn.x * xw[(r << LOGF) + f];
    }
    out[t] = acc;
}

// ---------------- pooling (segment sums over sorted batch) ----------------

__global__ void k_pool2(const float* __restrict__ h, const int* __restrict__ gstart,
                        float* __restrict__ psum) {
    int t = blockIdx.x * blockDim.x + threadIdx.x;
    if (t >= (N_GRAPHS << 5)) return;
    int g = t >> 5;
    int f = t & 31;
    int s = gstart[g], e = gstart[g + 1];
    float acc = 0.0f;
    for (int i = s; i < e; i++) acc += h[(i << 5) + f];
    psum[t] = acc;
}

__global__ void k_final(const float* __restrict__ psum, const int* __restrict__ gstart,
                        const float* __restrict__ b3, const float* __restrict__ Wl,
                        const float* __restrict__ bl, float* __restrict__ out) {
    int g = blockIdx.x * blockDim.x + threadIdx.x;
    if (g >= N_GRAPHS) return;
    int cnt = gstart[g + 1] - gstart[g];
    float o0 = bl[0], o1 = bl[1];
    if (cnt > 0) {
        float inv = 1.0f / (float)cnt;
#pragma unroll
        for (int fo = 0; fo < 32; fo++) {
            float p = psum[(g << 5) + fo] * inv + b3[fo];
            o0 += p * Wl[fo * 2 + 0];
            o1 += p * Wl[fo * 2 + 1];
        }
    }
    out[g * 2 + 0] = o0;
    out[g * 2 + 1] = o1;
}

// ---------------- launch ----------------

static inline int nblk(long n, int b) { return (int)((n + b - 1) / b); }

extern "C" void kernel_launch(void* const* d_in, const int* in_sizes, int n_in,
                              void* d_out, int out_size, void* d_ws, size_t ws_size,
                              hipStream_t stream) {
    const float* x     = (const float*)d_in[0];
    const int*   ei    = (const int*)d_in[1];
    const float* ew    = (const float*)d_in[2];
    const int*   batch = (const int*)d_in[3];
    const float* W1 = (const float*)d_in[4];
    const float* b1 = (const float*)d_in[5];
    const float* W2 = (const float*)d_in[6];
    const float* b2 = (const float*)d_in[7];
    const float* W3 = (const float*)d_in[8];
    const float* b3 = (const float*)d_in[9];
    const float* Wl = (const float*)d_in[10];
    const float* bl = (const float*)d_in[11];
    float* out = (float*)d_out;

    const int* row = ei;            // edge_index[0]
    const int* col = ei + N_EDGES;  // edge_index[1]

    // workspace layout (float-sized slots; packed needs 8B alignment: 500224*4 % 8 == 0)
    float*              dinv   = (float*)d_ws;                 // 500224 floats
    unsigned long long* packed = (unsigned long long*)(dinv + 500224);  // 500224 u64
    int*                rowptr = (int*)(dinv + 1500672);       // 500224 ints (uses 500001)
    float2*             ebuf   = (float2*)(dinv + 2000896);    // 8M float2 = 16M floats
    float*              bufA   = dinv + 18000896;              // 16M floats
    float*              bufB   = dinv + 34000896;              // 16M floats
    int*                bsum   = (int*)(dinv + 50000896);      // 512
    int*                gstart = (int*)(dinv + 50001408);      // 4104
    float*              psum   = dinv + 50005512;              // 131072  (end ~200.5 MB)

    int* idx = (int*)bufA;  // 8M ints alias bufA; consumed by k_build before k_mm1

    const int B = 256;

    // CSR build + norm precompute (ONE atomic per edge, total)
    k_init<<<nblk(N_NODES, B), B, 0, stream>>>(packed);
    k_hist<<<2048, B, 0, stream>>>(col, ew, packed, idx);
    k_dinv<<<nblk(N_NODES, B), B, 0, stream>>>(packed, dinv);
    k_scan1<<<SCAN_NB, SCAN_T, 0, stream>>>(packed, rowptr, bsum);
    k_scan2<<<1, SCAN2_T, 0, stream>>>(bsum);
    k_scan3<<<nblk(N_NODES, B), B, 0, stream>>>(rowptr, bsum);
    k_build<<<4096, B, 0, stream>>>(row, col, ew, idx, dinv, rowptr, ebuf);
    k_gstart<<<nblk(N_GRAPHS + 1, B), B, 0, stream>>>(batch, gstart);

    // layer 1: 9 -> 8
    k_mm1<<<nblk(N_NODES, B), B, 0, stream>>>(x, W1, bufA);
    k_gather<3><<<nblk((long)N_NODES * 8, B), B, 0, stream>>>(rowptr, ebuf, dinv, bufA, bufB);

    // layer 2: 8 -> 16
    k_mm_relu<8, 16><<<nblk(N_NODES, B), B, 0, stream>>>(bufB, b1, W2, bufA);
    k_gather<4><<<nblk((long)N_NODES * 16, B), B, 0, stream>>>(rowptr, ebuf, dinv, bufA, bufB);

    // layer 3: 16 -> 32
    k_mm_relu<16, 32><<<nblk(N_NODES, B), B, 0, stream>>>(bufB, b2, W3, bufA);
    k_gather<5><<<nblk((long)N_NODES * 32, B), B, 0, stream>>>(rowptr, ebuf, dinv, bufA, bufB);

    // pool + classifier
    k_pool2<<<nblk((long)N_GRAPHS * 32, B), B, 0, stream>>>(bufB, gstart, psum);
    k_final<<<nblk(N_GRAPHS, B), B, 0, stream>>>(psum, gstart, b3, Wl, bl, out);
}

// Round 9
// 1346.388 us; speedup vs baseline: 1.9505x; 1.0877x over previous
//
#include <hip/hip_runtime.h>

#define N_NODES 500000
#define N_EDGES 8000000
#define N_GRAPHS 4096

#define WSCALE 4294967296.0  // 2^32 fixed-point scale for weights
#define MASK44 ((1ULL << 44) - 1)

// ---------------- init: packed[i] = count 0 | weight 1.0 (self loop) ----------------

__global__ void k_init(unsigned long long* __restrict__ packed) {
    int i = blockIdx.x * blockDim.x + threadIdx.x;
    if (i < N_NODES) packed[i] = 1ULL << 32;  // deg = 1.0 fixed-point, count = 0
}

// ---------------- fused: xw1 = x@W1 (idle-VALU rider) + histogram atomic ----------
// single atomic per edge: count++ (hi 20b) + deg += w (lo 44b); old>>44 = slot idx.

__global__ void k_hist_mm1(const int* __restrict__ col, const float* __restrict__ w,
                           unsigned long long* __restrict__ packed, int* __restrict__ idx,
                           const float* __restrict__ x, const float* __restrict__ W1,
                           float* __restrict__ xw1) {
    int t0 = blockIdx.x * blockDim.x + threadIdx.x;
    int stride = gridDim.x * blockDim.x;
    // node part: xw1 = x @ W1  (9 -> 8)
    for (int i = t0; i < N_NODES; i += stride) {
        float xi[9];
#pragma unroll
        for (int f = 0; f < 9; f++) xi[f] = x[i * 9 + f];
        float o[8];
#pragma unroll
        for (int fo = 0; fo < 8; fo++) o[fo] = 0.0f;
#pragma unroll
        for (int fi = 0; fi < 9; fi++) {
            float a = xi[fi];
#pragma unroll
            for (int fo = 0; fo < 8; fo++) o[fo] += a * W1[fi * 8 + fo];
        }
        float4* po = reinterpret_cast<float4*>(xw1 + i * 8);
        po[0] = make_float4(o[0], o[1], o[2], o[3]);
        po[1] = make_float4(o[4], o[5], o[6], o[7]);
    }
    // edge part: one packed atomic per edge
    for (int e = t0; e < N_EDGES; e += stride) {
        unsigned long long wf = (unsigned long long)((double)w[e] * WSCALE + 0.5);
        unsigned long long add = (1ULL << 44) | wf;
        unsigned long long old = atomicAdd(&packed[col[e]], add);
        idx[e] = (int)(old >> 44);
    }
}

// ---------------- exclusive scan of counts (packed >> 44) -> rowptr; fused dinv ----

#define SCAN_T 256
#define SCAN_E 4
#define SCAN_ELEMS (SCAN_T * SCAN_E)  // 1024
#define SCAN_NB ((N_NODES + SCAN_ELEMS - 1) / SCAN_ELEMS)  // 489

__global__ void k_scan1(const unsigned long long* __restrict__ packed,
                        int* __restrict__ pre, int* __restrict__ bsum,
                        float* __restrict__ dinv) {
    __shared__ int sh[SCAN_T];
    int tid = threadIdx.x;
    int base = blockIdx.x * SCAN_ELEMS + tid * SCAN_E;
    int v[SCAN_E];
    int s = 0;
#pragma unroll
    for (int j = 0; j < SCAN_E; j++) {
        if (base + j < N_NODES) {
            unsigned long long p = packed[base + j];
            v[j] = (int)(p >> 44);
            float deg = (float)((double)(p & MASK44) * (1.0 / WSCALE));
            dinv[base + j] = rsqrtf(deg);  // deg >= 1 always
        } else v[j] = 0;
        s += v[j];
    }
    sh[tid] = s;
    __syncthreads();
    for (int off = 1; off < SCAN_T; off <<= 1) {
        int t = (tid >= off) ? sh[tid - off] : 0;
        __syncthreads();
        sh[tid] += t;
        __syncthreads();
    }
    int run = (tid == 0) ? 0 : sh[tid - 1];
    if (tid == SCAN_T - 1) bsum[blockIdx.x] = sh[SCAN_T - 1];
#pragma unroll
    for (int j = 0; j < SCAN_E; j++) {
        if (base + j < N_NODES) pre[base + j] = run;
        run += v[j];
    }
}

#define SCAN2_T 512
__global__ void k_scan2(int* __restrict__ bsum) {
    __shared__ int sh[SCAN2_T];
    int tid = threadIdx.x;
    sh[tid] = (tid < SCAN_NB) ? bsum[tid] : 0;
    __syncthreads();
    for (int off = 1; off < SCAN2_T; off <<= 1) {
        int t = (tid >= off) ? sh[tid - off] : 0;
        __syncthreads();
        sh[tid] += t;
        __syncthreads();
    }
    int ex = (tid == 0) ? 0 : sh[tid - 1];
    if (tid < SCAN_NB) bsum[tid] = ex;
}

__global__ void k_scan3(int* __restrict__ pre, const int* __restrict__ bsum) {
    int i = blockIdx.x * blockDim.x + threadIdx.x;
    if (i < N_NODES) pre[i] += bsum[i / SCAN_ELEMS];
    if (i == 0) pre[N_NODES] = N_EDGES;
}

// ---------------- build CSR edge records (NO atomics): ebuf[pos] = {norm, row} -----

__global__ void k_build(const int* __restrict__ row, const int* __restrict__ col,
                        const float* __restrict__ w, const int* __restrict__ idx,
                        const float* __restrict__ dinv, const int* __restrict__ rowptr,
                        float2* __restrict__ ebuf) {
    int e = blockIdx.x * blockDim.x + threadIdx.x;
    int stride = gridDim.x * blockDim.x;
    for (; e < N_EDGES; e += stride) {
        int c = col[e];
        int r = row[e];
        float nv = dinv[r] * w[e] * dinv[c];
        ebuf[rowptr[c] + idx[e]] = make_float2(nv, __int_as_float(r));
    }
}

// ---------------- graph boundaries (batch is sorted) ----------------

__global__ void k_gstart(const int* __restrict__ batch, int* __restrict__ gstart) {
    int g = blockIdx.x * blockDim.x + threadIdx.x;
    if (g > N_GRAPHS) return;
    if (g == N_GRAPHS) { gstart[g] = N_NODES; return; }
    int lo = 0, hi = N_NODES;  // lower_bound: first i with batch[i] >= g
    while (lo < hi) {
        int mid = (lo + hi) >> 1;
        if (batch[mid] < g) lo = mid + 1; else hi = mid;
    }
    gstart[g] = lo;
}

// ---------------- gather-reduce: out[c] = epi( sum_e norm*xw[r] + selfloop ) -------
// F lanes share one output node: broadcast 8B edge record, coalesced 4F-byte
// row gather, coalesced output write. Self-loop term = accumulator init.
// RELU epilogue applies (+bias, max 0) for layer-1 output.

template <int LOGF, bool RELU>
__global__ void k_gather(const int* __restrict__ rowptr, const float2* __restrict__ ebuf,
                         const float* __restrict__ dinv, const float* __restrict__ xw,
                         float* __restrict__ outb, const float* __restrict__ bias) {
    const int F = 1 << LOGF;
    int t = blockIdx.x * blockDim.x + threadIdx.x;
    int c = t >> LOGF;
    if (c >= N_NODES) return;
    int f = t & (F - 1);
    float d = dinv[c];
    float acc = d * d * xw[(c << LOGF) + f];
    int e0 = rowptr[c], e1 = rowptr[c + 1];
#pragma unroll 2
    for (int e = e0; e < e1; e++) {
        float2 rn = ebuf[e];
        int r = __float_as_int(rn.y);
        acc += rn.x * xw[(r << LOGF) + f];
    }
    if (RELU) acc = fmaxf(acc + bias[f], 0.0f);
    outb[t] = acc;
}

// ---------------- h2 = relu(agg2 @ W2 + b2)   (8 -> 16) ----------------

__global__ void k_mm2(const float* __restrict__ hin, const float* __restrict__ W,
                      const float* __restrict__ b, float* __restrict__ hout) {
    int i = blockIdx.x * blockDim.x + threadIdx.x;
    if (i >= N_NODES) return;
    float a[8];
    const float4* p = reinterpret_cast<const float4*>(hin + i * 8);
#pragma unroll
    for (int q = 0; q < 2; q++) {
        float4 v = p[q];
        a[q * 4 + 0] = v.x; a[q * 4 + 1] = v.y; a[q * 4 + 2] = v.z; a[q * 4 + 3] = v.w;
    }
    float o[16];
#pragma unroll
    for (int fo = 0; fo < 16; fo++) o[fo] = b[fo];
#pragma unroll
    for (int fi = 0; fi < 8; fi++) {
        float av = a[fi];
#pragma unroll
        for (int fo = 0; fo < 16; fo++) o[fo] += av * W[fi * 16 + fo];
    }
    float4* po = reinterpret_cast<float4*>(hout + i * 16);
#pragma unroll
    for (int q = 0; q < 4; q++)
        po[q] = make_float4(fmaxf(o[q * 4 + 0], 0.0f), fmaxf(o[q * 4 + 1], 0.0f),
                            fmaxf(o[q * 4 + 2], 0.0f), fmaxf(o[q * 4 + 3], 0.0f));
}

// ---------------- pooling over agg3 (16-dim; W3/b3 applied post-pool) --------------

__global__ void k_pool2(const float* __restrict__ h, const int* __restrict__ gstart,
                        float* __restrict__ psum) {
    int t = blockIdx.x * blockDim.x + threadIdx.x;
    if (t >= (N_GRAPHS << 4)) return;
    int g = t >> 4;
    int f = t & 15;
    int s = gstart[g], e = gstart[g + 1];
    float acc = 0.0f;
    for (int i = s; i < e; i++) acc += h[(i << 4) + f];
    psum[t] = acc;
}

// out[g] = ((mean agg3) @ W3 + b3) @ Wl + bl   (mean/W3 commute: layer 3 has no relu)

__global__ void k_final(const float* __restrict__ psum, const int* __restrict__ gstart,
                        const float* __restrict__ W3, const float* __restrict__ b3,
                        const float* __restrict__ Wl, const float* __restrict__ bl,
                        float* __restrict__ out) {
    int g = blockIdx.x * blockDim.x + threadIdx.x;
    if (g >= N_GRAPHS) return;
    int cnt = gstart[g + 1] - gstart[g];
    float o0 = bl[0], o1 = bl[1];
    if (cnt > 0) {
        float inv = 1.0f / (float)cnt;
        float p[16];
#pragma unroll
        for (int k = 0; k < 16; k++) p[k] = psum[(g << 4) + k] * inv;
#pragma unroll
        for (int fo = 0; fo < 32; fo++) {
            float t = b3[fo];
#pragma unroll
            for (int k = 0; k < 16; k++) t += p[k] * W3[k * 32 + fo];
            o0 += t * Wl[fo * 2 + 0];
            o1 += t * Wl[fo * 2 + 1];
        }
    }
    out[g * 2 + 0] = o0;
    out[g * 2 + 1] = o1;
}

// ---------------- launch ----------------

static inline int nblk(long n, int b) { return (int)((n + b - 1) / b); }

extern "C" void kernel_launch(void* const* d_in, const int* in_sizes, int n_in,
                              void* d_out, int out_size, void* d_ws, size_t ws_size,
                              hipStream_t stream) {
    const float* x     = (const float*)d_in[0];
    const int*   ei    = (const int*)d_in[1];
    const float* ew    = (const float*)d_in[2];
    const int*   batch = (const int*)d_in[3];
    const float* W1 = (const float*)d_in[4];
    const float* b1 = (const float*)d_in[5];
    const float* W2 = (const float*)d_in[6];
    const float* b2 = (const float*)d_in[7];
    const float* W3 = (const float*)d_in[8];
    const float* b3 = (const float*)d_in[9];
    const float* Wl = (const float*)d_in[10];
    const float* bl = (const float*)d_in[11];
    float* out = (float*)d_out;

    const int* row = ei;            // edge_index[0]
    const int* col = ei + N_EDGES;  // edge_index[1]

    // workspace layout (float-sized slots; packed 8B-aligned: 500224*4 % 8 == 0)
    float*              dinv   = (float*)d_ws;                          // 500224 floats
    unsigned long long* packed = (unsigned long long*)(dinv + 500224);  // 500224 u64
    int*                rowptr = (int*)(dinv + 1500672);                // 500224 ints
    float2*             ebuf   = (float2*)(dinv + 2000896);             // 8M float2
    float*              bufA   = dinv + 18000896;                       // 16M floats
    float*              bufB   = dinv + 34000896;                       // 16M floats
    int*                bsum   = (int*)(dinv + 50000896);               // 512
    int*                gstart = (int*)(dinv + 50001408);               // 4104
    float*              psum   = dinv + 50005512;                       // 65536

    int* idx = (int*)bufB;  // 8M ints alias bufB; dead after k_build, before gather<3,true> writes

    const int B = 256;

    // CSR build + norm precompute (ONE atomic per edge; mm1 rides in the atomic kernel)
    k_init<<<nblk(N_NODES, B), B, 0, stream>>>(packed);
    k_hist_mm1<<<2048, B, 0, stream>>>(col, ew, packed, idx, x, W1, bufA);
    k_scan1<<<SCAN_NB, SCAN_T, 0, stream>>>(packed, rowptr, bsum, dinv);
    k_scan2<<<1, SCAN2_T, 0, stream>>>(bsum);
    k_scan3<<<nblk(N_NODES, B), B, 0, stream>>>(rowptr, bsum);
    k_build<<<4096, B, 0, stream>>>(row, col, ew, idx, dinv, rowptr, ebuf);
    k_gstart<<<nblk(N_GRAPHS + 1, B), B, 0, stream>>>(batch, gstart);

    // layer 1: h1 = relu(A @ xw1 + b1)  at F=8
    k_gather<3, true><<<nblk((long)N_NODES * 8, B), B, 0, stream>>>(rowptr, ebuf, dinv, bufA, bufB, b1);

    // layer 2: aggregate BEFORE W2 (A commutes with matmul): agg2 = A @ h1 (F=8)
    k_gather<3, false><<<nblk((long)N_NODES * 8, B), B, 0, stream>>>(rowptr, ebuf, dinv, bufB, bufA, nullptr);
    k_mm2<<<nblk(N_NODES, B), B, 0, stream>>>(bufA, W2, b2, bufB);  // h2 = relu(agg2@W2+b2)

    // layer 3: aggregate BEFORE W3: agg3 = A @ h2 (F=16); W3+b3 applied post-pool
    k_gather<4, false><<<nblk((long)N_NODES * 16, B), B, 0, stream>>>(rowptr, ebuf, dinv, bufB, bufA, nullptr);

    // pool agg3 (16-dim) + fused W3/b3/classifier
    k_pool2<<<nblk((long)N_GRAPHS * 16, B), B, 0, stream>>>(bufA, gstart, psum);
    k_final<<<nblk(N_GRAPHS, B), B, 0, stream>>>(psum, gstart, W3, b3, Wl, bl, out);
}